// Round 9
// baseline (45940.558 us; speedup 1.0000x reference)
//
#include <hip/hip_runtime.h>

// ---------------------------------------------------------------------------
// MetaRNN (HyperNetwork-conditioned RNN), MI355X gfx950.  v10
//   1) GEMM (MFMA, split-bf16 x3): xW = x @ Wih^T, xH = x @ Wih_hy_x^T
//   2) scan: 8 blocks x 1024 thr (16 waves, 4/SIMD). TWO time-offset groups
//      of 8 waves; each group = the v4 schedule (best: 4232us) on its own
//      16 batch rows + own LDS state; group 1 runs one barrier-slot behind.
//      Every SIMD hosts 2+2 waves in DIFFERENT phases -> heterogeneous
//      latency overlap that lockstep (v6) could not give.
//      LDS: 2x group frags (76KB) + shared HY-hi kt0..7 (64KB) = 140KB.
//      HY-hi kt8..11 streams through the idle W-slot registers (no VGPR add).
//      Split-bf16 3-term products (absmax 0.0039 validated v1-v9).
// ---------------------------------------------------------------------------

#define DEVI __device__ __forceinline__

typedef __bf16 bf16x8 __attribute__((ext_vector_type(8)));
typedef float f32x4 __attribute__((ext_vector_type(4)));
typedef unsigned short u16;
typedef unsigned int u32;
typedef u32 u32x4 __attribute__((ext_vector_type(4)));
typedef u16 u16x8 __attribute__((ext_vector_type(8)));

constexpr int B_ = 256, T_ = 512, D_ = 256, H_ = 256, HH_ = 128, E_ = 32;
constexpr int BT = B_ * T_;

// fragment-buffer offsets (u16 elements), per layer
constexpr int OXW = 0,      PXW = 16 * 8 * 512;   // Wih      [16nt][8kt]
constexpr int OXH = 131072, PXH = 8 * 8 * 512;    // Wih_hy_x [8nt][8kt]
constexpr int OHY = 196608, PHY = 8 * 12 * 512;   // [U_hy|Whh_hy] [8nt][12kt]
constexpr int OWHH = 294912, PWHH = 16 * 8 * 512; // Whh      [16nt][8kt]
constexpr int OWHZ = 425984, PWHZ = 6 * 4 * 512;  // Whz flat [6nt][4kt]
constexpr int OWZD = 450560, PWZD = 48 * 512;     // Wzd      [3g][16nt][1kt]
constexpr int LSTRIDE = 499712;                   // u16 per layer

constexpr size_t WS_XW = 0;
constexpr size_t WS_XH = (size_t)BT * H_ * 4;
constexpr size_t WS_FR = WS_XH + (size_t)BT * HH_ * 4;

DEVI u16 f2bf(float v) {            // round-to-nearest-even fp32 -> bf16 bits
  u32 u = __float_as_uint(v);
  u += 0x7fffu + ((u >> 16) & 1u);
  return (u16)(u >> 16);
}
DEVI float bf2f(u16 s) { return __uint_as_float(((u32)s) << 16); }
DEVI void split2(float v, u16 &hi, u16 &lo) {
  hi = f2bf(v);
  lo = f2bf(v - bf2f(hi));          // exact subtraction
}
DEVI bf16x8 ldfrag(const u16 *p) {
  u32x4 v = *reinterpret_cast<const u32x4 *>(p);
  return __builtin_bit_cast(bf16x8, v);
}
// Pin a fragment in registers (opaque to the optimizer -> no remat/sink).
DEVI void pin(bf16x8 &x) {
  u32x4 t = __builtin_bit_cast(u32x4, x);
  asm volatile("" : "+v"(t));
  x = __builtin_bit_cast(bf16x8, t);
}
DEVI f32x4 mfma3(bf16x8 ah, bf16x8 al, bf16x8 bh, bf16x8 bl, f32x4 c) {
  c = __builtin_amdgcn_mfma_f32_16x16x32_bf16(ah, bh, c, 0, 0, 0);
  c = __builtin_amdgcn_mfma_f32_16x16x32_bf16(ah, bl, c, 0, 0, 0);
  c = __builtin_amdgcn_mfma_f32_16x16x32_bf16(al, bh, c, 0, 0, 0);
  return c;
}
DEVI float tanh_fast(float x) {
  float e = __expf(2.0f * x);       // inf-safe: ->1 / ->-1 at extremes
  return 1.0f - 2.0f / (e + 1.0f);
}
// Raw barrier: LDS ordering enforced (lgkmcnt(0)), vmem loads stay in flight.
DEVI void block_sync() {
  asm volatile("s_waitcnt lgkmcnt(0)\n\ts_barrier" ::: "memory");
}

// ---------------------------------------------------------------------------
// prep: split all weights to bf16 hi/lo and lay out as 16x16x32 B-fragments.
// fragment: element j, lane l  <-  W[nt*16 + (l&15), kt*32 + (l>>4)*8 + j]
// ---------------------------------------------------------------------------
__global__ void metarnn_prep(const float *__restrict__ Wih,
                             const float *__restrict__ Whh,
                             const float *__restrict__ Wih_hy,
                             const float *__restrict__ Whh_hy,
                             const float *__restrict__ Whz,
                             const float *__restrict__ Wzd,
                             u16 *__restrict__ fr) {
  int gid = blockIdx.x * 256 + threadIdx.x;
  int lane = gid & 63;
  int e = gid >> 6;
  if (e >= 2 * 488) return;
  int l = e / 488, r = e - l * 488;
  u16 *base = fr + (size_t)l * LSTRIDE;
  int rowL = lane & 15, kg = (lane >> 4) << 3;

  const float *src = nullptr;
  int ld = 0, nt = 0, kt = 0, KT = 1, special = 0;
  u16 *dh = nullptr, *dl = nullptr;
  if (r < 128) {            // Wih [H,D]
    nt = r >> 3; kt = r & 7; KT = 8;
    src = Wih + (size_t)l * H_ * D_; ld = D_;
    dh = base + OXW; dl = dh + PXW;
  } else if (r < 192) {     // Wih_hy x-part [HH, 0:256]
    r -= 128; nt = r >> 3; kt = r & 7; KT = 8;
    src = Wih_hy + (size_t)l * HH_ * (D_ + H_); ld = D_ + H_;
    dh = base + OXH; dl = dh + PXH;
  } else if (r < 288) {     // concat [U_hy | Whh_hy]  [HH, 384]
    r -= 192; nt = r / 12; kt = r - nt * 12; KT = 12; special = 1;
    dh = base + OHY; dl = dh + PHY;
  } else if (r < 416) {     // Whh [H,H]
    r -= 288; nt = r >> 3; kt = r & 7; KT = 8;
    src = Whh + (size_t)l * H_ * H_; ld = H_;
    dh = base + OWHH; dl = dh + PWHH;
  } else if (r < 440) {     // Whz flat [96, HH]
    r -= 416; nt = r >> 2; kt = r & 3; KT = 4;
    src = Whz + (size_t)l * 3 * E_ * HH_; ld = HH_;
    dh = base + OWHZ; dl = dh + PWHZ;
  } else {                  // Wzd per g: [H, E]
    r -= 440; int g = r >> 4; nt = r & 15; kt = 0; KT = 1;
    src = Wzd + (size_t)(l * 3 + g) * H_ * E_; ld = E_;
    dh = base + OWZD + g * 16 * 512; dl = base + OWZD + PWZD + g * 16 * 512;
  }
  int row = nt * 16 + rowL;
  long dof = ((long)(nt * KT + kt) * 64 + lane) * 8;
  for (int j = 0; j < 8; ++j) {
    int k = kt * 32 + kg + j;
    float v;
    if (special) {
      v = (k < 256) ? Wih_hy[((size_t)l * HH_ + row) * (D_ + H_) + 256 + k]
                    : Whh_hy[((size_t)l * HH_ + row) * HH_ + (k - 256)];
    } else {
      v = src[(size_t)row * ld + k];
    }
    u16 hi, lo;
    split2(v, hi, lo);
    dh[dof + j] = hi;
    dl[dof + j] = lo;
  }
}

// ---------------------------------------------------------------------------
// GEMM: xW[m,0:256], xH[m,0:128] = x[m,0:256] @ {Wih, Wih_hy_x}^T
// ---------------------------------------------------------------------------
__global__ __launch_bounds__(256, 1) void metarnn_gemm(
    const float *__restrict__ x, const u16 *__restrict__ fr,
    float *__restrict__ xW, float *__restrict__ xH) {
  int w = threadIdx.x >> 6, lane = threadIdx.x & 63;
  int m0 = blockIdx.x * 32;
  int rowL = lane & 15, kg = (lane >> 4) << 3;
  f32x4 acc[2][6] = {};
  const u16 *fxw_h = fr + OXW, *fxw_l = fxw_h + PXW;
  const u16 *fxh_h = fr + OXH, *fxh_l = fxh_h + PXH;

  for (int kt = 0; kt < 8; ++kt) {
    bf16x8 ah[2], al[2];
    for (int s = 0; s < 2; ++s) {
      const float *xp = x + (size_t)(m0 + s * 16 + rowL) * 256 + kt * 32 + kg;
      u16x8 vh, vl;
#pragma unroll
      for (int j = 0; j < 8; ++j) {
        u16 hi, lo;
        split2(xp[j], hi, lo);
        vh[j] = hi; vl[j] = lo;
      }
      ah[s] = __builtin_bit_cast(bf16x8, vh);
      al[s] = __builtin_bit_cast(bf16x8, vl);
    }
#pragma unroll
    for (int q = 0; q < 6; ++q) {
      int nt = w * 6 + q;
      long o = (nt < 16) ? ((long)(nt * 8 + kt) * 64 + lane) * 8
                         : ((long)((nt - 16) * 8 + kt) * 64 + lane) * 8;
      const u16 *bh = (nt < 16) ? fxw_h + o : fxh_h + o;
      const u16 *bl = (nt < 16) ? fxw_l + o : fxh_l + o;
      bf16x8 B0 = ldfrag(bh), B1 = ldfrag(bl);
      acc[0][q] = mfma3(ah[0], al[0], B0, B1, acc[0][q]);
      acc[1][q] = mfma3(ah[1], al[1], B0, B1, acc[1][q]);
    }
  }
  for (int s = 0; s < 2; ++s)
    for (int q = 0; q < 6; ++q) {
      int nt = w * 6 + q;
#pragma unroll
      for (int r = 0; r < 4; ++r) {
        int row = m0 + s * 16 + (lane >> 4) * 4 + r;
        if (nt < 16)
          xW[(size_t)row * H_ + nt * 16 + rowL] = acc[s][q][r];
        else
          xH[(size_t)row * HH_ + (nt - 16) * 16 + rowL] = acc[s][q][r];
      }
    }
}

// ---------------------------------------------------------------------------
// scan v10: 8 blocks x 1024 threads. group g = tid>>9 (8 waves each),
// wv = wave role 0..7 (v4 roles). Group 1 runs one barrier-slot behind.
// Slot loop: s = 0..3T;  g0: A@s%3==0, B@1, C@2;  g1: A@1, B@2, C@0 (s>0).
// Phases (per group, v4-identical): A=[P1 aA/aW + P2 hh], B=[P3 z], C=[P5+P6].
// ---------------------------------------------------------------------------
__global__ __launch_bounds__(1024, 4) void metarnn_scan(
    const float *__restrict__ xW, const float *__restrict__ xH,
    const u16 *__restrict__ fr, const float *__restrict__ bmain,
    const float *__restrict__ bhy, const float *__restrict__ bz,
    float *__restrict__ y, float *__restrict__ hlast, int layer, int isLast) {
  __shared__ __align__(16) u16 hy_lds[8 * 8 * 512];          // HY-hi kt0..7
  __shared__ __align__(16) u16 hcG_h[2][8 * 512];
  __shared__ __align__(16) u16 hcG_l[2][8 * 512];
  __shared__ __align__(16) u16 hhbG_h[2][2][4 * 512];
  __shared__ __align__(16) u16 hhbG_l[2][2][4 * 512];
  __shared__ __align__(16) u16 zfG_h[2][3 * 512];
  __shared__ __align__(16) u16 zfG_l[2][3 * 512];

  int tid = threadIdx.x, w = tid >> 6, lane = tid & 63;
  int g = tid >> 9, wv = w & 7, gtid = tid & 511;
  int bs = blockIdx.x * 32 + g * 16;
  int rowL = lane & 15, colG = lane >> 4;

  u16 *hc_h = hcG_h[g], *hc_l = hcG_l[g];
  u16 (*hhb_h)[4 * 512] = hhbG_h[g];
  u16 (*hhb_l)[4 * 512] = hhbG_l[g];
  u16 *zf_h = zfG_h[g], *zf_l = zfG_l[g];

  const u16 *FHY = fr + OHY, *FHYl = FHY + PHY;
  const u16 *FWH = fr + OWHH, *FWHl = FWH + PWHH;
  const u16 *FWZ = fr + OWHZ, *FWZl = FWZ + PWHZ;
  const u16 *FZD = fr + OWZD, *FZDl = FZD + PWZD;

  for (int i = gtid; i < 8 * 512; i += 512) { hc_h[i] = 0; hc_l[i] = 0; }
  for (int i = gtid; i < 2 * 4 * 512; i += 512) {
    (&hhb_h[0][0])[i] = 0;
    (&hhb_l[0][0])[i] = 0;
  }
  for (int i = gtid; i < 3 * 512; i += 512) { zf_h[i] = 0; zf_l[i] = 0; }
  // shared HY-hi kt0..7 -> LDS (once, both groups cooperate)
  for (int c = tid; c < 8 * 8 * 64; c += 1024) {
    int tile = c >> 9, rem = c & 511, kt = rem >> 6, ln = rem & 63;
    *reinterpret_cast<u32x4 *>(&hy_lds[((tile * 8 + kt) * 64 + ln) * 8]) =
        *reinterpret_cast<const u32x4 *>(
            FHY + ((long)(tile * 12 + kt) * 64 + ln) * 8);
  }

  // ---- PINNED: Whh-lo (64 regs) + Whz (32 regs) ---------------------------
  bf16x8 RWL[2][8];
#pragma unroll
  for (int p = 0; p < 2; ++p)
#pragma unroll
    for (int kt = 0; kt < 8; ++kt) {
      long o = ((long)((2 * wv + p) * 8 + kt) * 64 + lane) * 8;
      RWL[p][kt] = ldfrag(FWHl + o);
      pin(RWL[p][kt]);
    }
  bf16x8 zresH[4], zresL[4];
  {
    int wz = (wv < 6) ? wv : 0;
#pragma unroll
    for (int kk = 0; kk < 4; ++kk) {
      long o = ((long)(wz * 4 + kk) * 64 + lane) * 8;
      zresH[kk] = ldfrag(FWZ + o);  pin(zresH[kk]);
      zresL[kk] = ldfrag(FWZl + o); pin(zresL[kk]);
    }
  }

  // ---- hoisted biases -----------------------------------------------------
  int c2 = 16 * wv + rowL;                      // hyper col (0..127)
  float bhv = bhy[layer * HH_ + c2];
  float bzv = (wv < 6) ? bz[layer * 3 * E_ + c2] : 0.0f;
  float bbv[2];
  bbv[0] = bmain[layer * H_ + 32 * wv + rowL];
  bbv[1] = bmain[layer * H_ + 32 * wv + 16 + rowL];

  // ---- streamed slots: Whh-hi (kt<8) / HY-hi (kt>=8, reuses bWH[S][0]) ----
  bf16x8 bWH[3][2], bYL[3];
#define LOAD_SLOT(S, KT)                                                      \
  {                                                                           \
    bYL[S] = ldfrag(FHYl + ((long)(wv * 12 + (KT)) * 64 + lane) * 8);         \
    if ((KT) < 8) {                                                           \
      bWH[S][0] =                                                             \
          ldfrag(FWH + ((long)((2 * wv) * 8 + (KT)) * 64 + lane) * 8);        \
      bWH[S][1] =                                                             \
          ldfrag(FWH + ((long)((2 * wv + 1) * 8 + (KT)) * 64 + lane) * 8);    \
    } else {                                                                  \
      bWH[S][0] = ldfrag(FHY + ((long)(wv * 12 + (KT)) * 64 + lane) * 8);     \
    }                                                                         \
  }
  LOAD_SLOT(0, 0) LOAD_SLOT(1, 1) LOAD_SLOT(2, 2)

  // ---- x inputs for t=0 ---------------------------------------------------
  float xhA[4], xwA[2][4];
#pragma unroll
  for (int r = 0; r < 4; ++r) {
    size_t row = (size_t)(bs + 4 * colG + r) * T_;
    xhA[r] = xH[row * HH_ + c2];
    xwA[0][r] = xW[row * H_ + 32 * wv + rowL];
    xwA[1][r] = xW[row * H_ + 32 * wv + 16 + rowL];
  }

  __syncthreads();                  // once; full drain acceptable here

  // ---- persistent per-phase state ----------------------------------------
  f32x4 aW0 = {}, aW1 = {};
  bf16x8 D0h[2], D0l[2], D1h[2], D1l[2], D2h[2], D2l[2];
  int tA = 0, tB = 0, tC = 0, m3 = 0;

  for (int s = 0; s <= 3 * T_; ++s) {
    const bool doA = (m3 == (g ? 1 : 0)) && (tA < T_);
    const bool doB = (m3 == (g ? 2 : 1)) && (tB < T_);
    const bool doC = (m3 == (g ? 0 : 2)) && (tC < T_) && (g == 0 || s > 0);

    if (doA) {
      // ---- PHASE A: P1 (aA, aW) + P2 (hh) ---------------------------------
      const int t = tA, pr = t & 1;
      f32x4 aAe = {}, aAo = {};
      aW0 = f32x4{};
      aW1 = f32x4{};
      __builtin_amdgcn_s_setprio(1);
#pragma unroll
      for (int j = 0; j < 12; ++j) {
        const int s3 = j % 3;
        bf16x8 ah, al;
        if (j < 8) {
          ah = ldfrag(&hc_h[j * 512 + lane * 8]);
          al = ldfrag(&hc_l[j * 512 + lane * 8]);
        } else {
          ah = ldfrag(&hhb_h[pr ^ 1][(j - 8) * 512 + lane * 8]);
          al = ldfrag(&hhb_l[pr ^ 1][(j - 8) * 512 + lane * 8]);
        }
        bf16x8 yh = (j < 8) ? ldfrag(&hy_lds[(wv * 8 + j) * 512 + lane * 8])
                            : bWH[s3][0];
        if (j & 1) aAo = mfma3(ah, al, yh, bYL[s3], aAo);
        else       aAe = mfma3(ah, al, yh, bYL[s3], aAe);
        if (j < 8) {
          aW0 = mfma3(ah, al, bWH[s3][0], RWL[0][j], aW0);
          aW1 = mfma3(ah, al, bWH[s3][1], RWL[1][j], aW1);
        }
        if (j < 9) LOAD_SLOT(s3, j + 3)
      }
      __builtin_amdgcn_s_setprio(0);
      f32x4 aA;
#pragma unroll
      for (int r = 0; r < 4; ++r) aA[r] = aAe[r] + aAo[r];

      // tail issues: next-A slots, D0, then P2, then xh (youngest = HBM)
      LOAD_SLOT(0, 0) LOAD_SLOT(1, 1) LOAD_SLOT(2, 2)
#pragma unroll
      for (int p = 0; p < 2; ++p) {
        long o = ((long)(2 * wv + p) * 64 + lane) * 8;
        D0h[p] = ldfrag(FZD + o);
        D0l[p] = ldfrag(FZDl + o);
      }
      {
        int kfr = wv >> 1;
        int hb2 = 2 * (wv & 1) + (rowL >> 3);
        int j7 = rowL & 7;
#pragma unroll
        for (int r = 0; r < 4; ++r) {
          float v = tanh_fast(aA[r] + xhA[r] + bhv);
          u16 hi, lo;
          split2(v, hi, lo);
          int di = kfr * 512 + ((4 * colG + r) + 16 * hb2) * 8 + j7;
          hhb_h[pr][di] = hi;
          hhb_l[pr][di] = lo;
        }
      }
#pragma unroll
      for (int r = 0; r < 4; ++r) {   // t=T-1 reads past xH into fr: benign
        xhA[r] = xH[((size_t)(bs + 4 * colG + r) * T_ + t + 1) * HH_ + c2];
      }
      tA++;
    }

    if (doB) {
      // ---- PHASE B: D1/D2 issue + P3 (z) ----------------------------------
      const int t = tB, pr = t & 1;
#pragma unroll
      for (int p = 0; p < 2; ++p) {
        long o1 = ((long)(16 + 2 * wv + p) * 64 + lane) * 8;
        long o2 = ((long)(32 + 2 * wv + p) * 64 + lane) * 8;
        D1h[p] = ldfrag(FZD + o1);
        D1l[p] = ldfrag(FZDl + o1);
        D2h[p] = ldfrag(FZD + o2);
        D2l[p] = ldfrag(FZDl + o2);
      }
      if (wv < 6) {
        f32x4 aZ = {};
#pragma unroll
        for (int kk = 0; kk < 4; ++kk) {
          bf16x8 ah = ldfrag(&hhb_h[pr][kk * 512 + lane * 8]);
          bf16x8 al = ldfrag(&hhb_l[pr][kk * 512 + lane * 8]);
          aZ = mfma3(ah, al, zresH[kk], zresL[kk], aZ);
        }
        int gq = c2 >> 5;
        int hb3 = 2 * (wv & 1) + (rowL >> 3);
        int j7 = rowL & 7;
#pragma unroll
        for (int r = 0; r < 4; ++r) {
          float v = aZ[r] + bzv;
          u16 hi, lo;
          split2(v, hi, lo);
          int di = gq * 512 + ((4 * colG + r) + 16 * hb3) * 8 + j7;
          zf_h[di] = hi;
          zf_l[di] = lo;
        }
      }
      tB++;
    }

    if (doC) {
      // ---- PHASE C: P5 (d, arg) + P6 (h, writes) --------------------------
      const int t = tC;
      float arg[2][4];
#pragma unroll
      for (int p = 0; p < 2; ++p)
#pragma unroll
        for (int r = 0; r < 4; ++r) arg[p][r] = bbv[p];
      {
        bf16x8 zh = ldfrag(&zf_h[0 * 512 + lane * 8]);
        bf16x8 zl = ldfrag(&zf_l[0 * 512 + lane * 8]);
#pragma unroll
        for (int p = 0; p < 2; ++p) {
          f32x4 zero = {};
          f32x4 dg = mfma3(zh, zl, D0h[p], D0l[p], zero);
#pragma unroll
          for (int r = 0; r < 4; ++r) arg[p][r] += dg[r] * xwA[p][r];
        }
      }
#pragma unroll
      for (int r = 0; r < 4; ++r) {   // xw for t+1 (after last use; HBM)
        size_t row = (size_t)(bs + 4 * colG + r) * T_ + t + 1;
        xwA[0][r] = xW[row * H_ + 32 * wv + rowL];
        xwA[1][r] = xW[row * H_ + 32 * wv + 16 + rowL];
      }
      {
        bf16x8 zh = ldfrag(&zf_h[1 * 512 + lane * 8]);
        bf16x8 zl = ldfrag(&zf_l[1 * 512 + lane * 8]);
#pragma unroll
        for (int p = 0; p < 2; ++p) {
          f32x4 zero = {};
          f32x4 dg = mfma3(zh, zl, D1h[p], D1l[p], zero);
#pragma unroll
          for (int r = 0; r < 4; ++r)
            arg[p][r] += dg[r] * ((p == 0) ? aW0[r] : aW1[r]);
        }
      }
      {
        bf16x8 zh = ldfrag(&zf_h[2 * 512 + lane * 8]);
        bf16x8 zl = ldfrag(&zf_l[2 * 512 + lane * 8]);
#pragma unroll
        for (int p = 0; p < 2; ++p) {
          f32x4 zero = {};
          f32x4 dg = mfma3(zh, zl, D2h[p], D2l[p], zero);
#pragma unroll
          for (int r = 0; r < 4; ++r) arg[p][r] += dg[r];
        }
      }
#pragma unroll
      for (int p = 0; p < 2; ++p) {
        int c = 32 * wv + 16 * p + rowL;
        int hb6 = 2 * p + (rowL >> 3);
        int j7 = rowL & 7;
#pragma unroll
        for (int r = 0; r < 4; ++r) {
          int m = 4 * colG + r;
          float h = tanh_fast(arg[p][r]);
          size_t gi = (size_t)(bs + m) * T_ + t;
          y[gi * H_ + c] = h;
          if (isLast && t == T_ - 1) hlast[(size_t)(bs + m) * H_ + c] = h;
          u16 hi, lo;
          split2(h, hi, lo);
          int di = (c >> 5) * 512 + (m + 16 * hb6) * 8 + j7;
          hc_h[di] = hi;
          hc_l[di] = lo;
        }
      }
      tC++;
    }

    block_sync();
    m3 = (m3 == 2) ? 0 : m3 + 1;
  }
#undef LOAD_SLOT
}

// ---------------------------------------------------------------------------
extern "C" void kernel_launch(void *const *d_in, const int *in_sizes, int n_in,
                              void *d_out, int out_size, void *d_ws,
                              size_t ws_size, hipStream_t stream) {
  (void)in_sizes; (void)n_in; (void)out_size; (void)ws_size;
  const float *input  = (const float *)d_in[0];
  const float *Wih    = (const float *)d_in[1];
  const float *Whh    = (const float *)d_in[2];
  const float *b      = (const float *)d_in[3];
  const float *Wih_hy = (const float *)d_in[4];
  const float *Whh_hy = (const float *)d_in[5];
  const float *b_hy   = (const float *)d_in[6];
  const float *Whz    = (const float *)d_in[7];
  const float *bz     = (const float *)d_in[8];
  const float *Wzd    = (const float *)d_in[9];

  float *out = (float *)d_out;
  float *xW = (float *)((char *)d_ws + WS_XW);
  float *xH = (float *)((char *)d_ws + WS_XH);
  u16 *fr = (u16 *)((char *)d_ws + WS_FR);
  float *hlast = out + (size_t)BT * H_;

  metarnn_prep<<<dim3(244), dim3(256), 0, stream>>>(Wih, Whh, Wih_hy, Whh_hy,
                                                    Whz, Wzd, fr);
  for (int l = 0; l < 2; ++l) {
    const float *xsrc = (l == 0) ? input : out;   // layer1 reads layer0 output
    const u16 *frl = fr + (size_t)l * LSTRIDE;
    metarnn_gemm<<<dim3(BT / 32), dim3(256), 0, stream>>>(xsrc, frl, xW, xH);
    metarnn_scan<<<dim3(8), dim3(1024), 0, stream>>>(
        xW, xH, frl, b, b_hy, bz, out, hlast, l, (l == 1) ? 1 : 0);
  }
}

// Round 11
// 14467.233 us; speedup vs baseline: 3.1755x; 3.1755x over previous
//
#include <hip/hip_runtime.h>

// ---------------------------------------------------------------------------
// MetaRNN (HyperNetwork-conditioned RNN), MI355X gfx950.  v12
//   = v11's algebra (z-phase composed away: d_g = hh @ M_g^T + db_g with
//     M_g = Wzd_g@Whz_g, db_g = Wzd_g@bz_g) with a STRICTLY SMALLER ws
//     footprint than the 9x-validated v4 (suspected v11 failure: ws overflow
//     corrupting an adjacent allocation across graph replays):
//   - fr holds only HY/Whh/M frags (LSTRIDE 425984 u16 < v4's 499712);
//     gemm splits raw f32 weights on the fly (bit-identical fragments).
//   - compose kernel gone: prep computes M inline; scan computes db inline.
//   - t+1 input loads guarded (no OOB reads).
//   Scan: A[P1 aA/aW + P2 hh] -BA-> C[d-matmul + P6 h] -BC-> (2 barriers/step)
//   Split-bf16 3-term products (absmax 0.0039, bit-identical to v11 call 1).
// ---------------------------------------------------------------------------

#define DEVI __device__ __forceinline__

typedef __bf16 bf16x8 __attribute__((ext_vector_type(8)));
typedef float f32x4 __attribute__((ext_vector_type(4)));
typedef unsigned short u16;
typedef unsigned int u32;
typedef u32 u32x4 __attribute__((ext_vector_type(4)));
typedef u16 u16x8 __attribute__((ext_vector_type(8)));

constexpr int B_ = 256, T_ = 512, D_ = 256, H_ = 256, HH_ = 128, E_ = 32;
constexpr int BT = B_ * T_;

// fragment-buffer offsets (u16 elements), per layer — scan-only weights
constexpr int OHY = 0,      PHY = 8 * 12 * 512;   // [U_hy|Whh_hy] [8nt][12kt]
constexpr int OWHH = 98304, PWHH = 16 * 8 * 512;  // Whh      [16nt][8kt]
constexpr int OM = 229376,  POM = 192 * 512;      // M        [3g][16nt][4kt]
constexpr int LSTRIDE = 425984;                   // u16 per layer (< v4)

constexpr size_t WS_XW = 0;
constexpr size_t WS_XH = (size_t)BT * H_ * 4;
constexpr size_t WS_FR = WS_XH + (size_t)BT * HH_ * 4;
// total ws usage: WS_FR + 2*LSTRIDE*2 = 203,030,528 B  (v4 used 203,325,440)

DEVI u16 f2bf(float v) {            // round-to-nearest-even fp32 -> bf16 bits
  u32 u = __float_as_uint(v);
  u += 0x7fffu + ((u >> 16) & 1u);
  return (u16)(u >> 16);
}
DEVI float bf2f(u16 s) { return __uint_as_float(((u32)s) << 16); }
DEVI void split2(float v, u16 &hi, u16 &lo) {
  hi = f2bf(v);
  lo = f2bf(v - bf2f(hi));          // exact subtraction
}
DEVI bf16x8 ldfrag(const u16 *p) {
  u32x4 v = *reinterpret_cast<const u32x4 *>(p);
  return __builtin_bit_cast(bf16x8, v);
}
// Pin a fragment in registers (opaque to the optimizer -> no remat/sink).
DEVI void pin(bf16x8 &x) {
  u32x4 t = __builtin_bit_cast(u32x4, x);
  asm volatile("" : "+v"(t));
  x = __builtin_bit_cast(bf16x8, t);
}
DEVI f32x4 mfma3(bf16x8 ah, bf16x8 al, bf16x8 bh, bf16x8 bl, f32x4 c) {
  c = __builtin_amdgcn_mfma_f32_16x16x32_bf16(ah, bh, c, 0, 0, 0);
  c = __builtin_amdgcn_mfma_f32_16x16x32_bf16(ah, bl, c, 0, 0, 0);
  c = __builtin_amdgcn_mfma_f32_16x16x32_bf16(al, bh, c, 0, 0, 0);
  return c;
}
DEVI float tanh_fast(float x) {
  float e = __expf(2.0f * x);       // inf-safe: ->1 / ->-1 at extremes
  return 1.0f - 2.0f / (e + 1.0f);
}
// Raw barrier: LDS ordering enforced (lgkmcnt(0)), vmem loads stay in flight.
DEVI void block_sync() {
  asm volatile("s_waitcnt lgkmcnt(0)\n\ts_barrier" ::: "memory");
}

// ---------------------------------------------------------------------------
// prep: split scan weights to bf16 hi/lo 16x16x32 B-fragments.
// fragment: element j, lane l  <-  W[nt*16 + (l&15), kt*32 + (l>>4)*8 + j]
// entries/layer: HY 96, Whh 128, M 192 -> 416 (M computed on the fly).
// ---------------------------------------------------------------------------
__global__ void metarnn_prep(const float *__restrict__ Whh,
                             const float *__restrict__ Wih_hy,
                             const float *__restrict__ Whh_hy,
                             const float *__restrict__ Whz,
                             const float *__restrict__ Wzd,
                             u16 *__restrict__ fr) {
  int gid = blockIdx.x * 256 + threadIdx.x;
  int lane = gid & 63;
  int e = gid >> 6;
  if (e >= 2 * 416) return;
  int l = e / 416, r = e - l * 416;
  u16 *base = fr + (size_t)l * LSTRIDE;
  int rowL = lane & 15, kg = (lane >> 4) << 3;

  if (r < 96) {             // HY concat [U_hy | Whh_hy]  [HH, 384]
    int nt = r / 12, kt = r - nt * 12;
    u16 *dh = base + OHY, *dl = dh + PHY;
    int row = nt * 16 + rowL;
    long dof = ((long)(nt * 12 + kt) * 64 + lane) * 8;
    for (int j = 0; j < 8; ++j) {
      int k = kt * 32 + kg + j;
      float v = (k < 256)
                    ? Wih_hy[((size_t)l * HH_ + row) * (D_ + H_) + 256 + k]
                    : Whh_hy[((size_t)l * HH_ + row) * HH_ + (k - 256)];
      u16 hi, lo;
      split2(v, hi, lo);
      dh[dof + j] = hi;
      dl[dof + j] = lo;
    }
  } else if (r < 224) {     // Whh [H,H]
    int m = r - 96;
    int nt = m >> 3, kt = m & 7;
    u16 *dh = base + OWHH, *dl = dh + PWHH;
    int row = nt * 16 + rowL;
    long dof = ((long)(nt * 8 + kt) * 64 + lane) * 8;
    const float *src = Whh + (size_t)l * H_ * H_;
    for (int j = 0; j < 8; ++j) {
      u16 hi, lo;
      split2(src[(size_t)row * H_ + kt * 32 + kg + j], hi, lo);
      dh[dof + j] = hi;
      dl[dof + j] = lo;
    }
  } else {                  // M_g = Wzd_g @ Whz_g   [3g][256,128], on the fly
    int m = r - 224;
    int g = m >> 6, rem = m & 63;
    int nt = rem >> 2, kt = rem & 3;
    u16 *dh = base + OM + (size_t)(g * 64) * 512, *dl = dh + POM;
    int row = nt * 16 + rowL;
    long dof = ((long)(nt * 4 + kt) * 64 + lane) * 8;
    int lg = l * 3 + g;
    const float *wz = Wzd + ((size_t)lg * 256 + row) * 32;
    const float *whB = Whz + (size_t)lg * 32 * 128;
    for (int j = 0; j < 8; ++j) {
      int k = kt * 32 + kg + j;
      float acc = 0.0f;
      for (int ee = 0; ee < 32; ++ee) acc += wz[ee] * whB[ee * 128 + k];
      u16 hi, lo;
      split2(acc, hi, lo);
      dh[dof + j] = hi;
      dl[dof + j] = lo;
    }
  }
}

// ---------------------------------------------------------------------------
// GEMM: xW[m,0:256], xH[m,0:128] = x[m,0:256] @ {Wih, Wih_hy_x}^T
// Weights read raw from d_in, split2 on the fly (bit-identical fragments).
// ---------------------------------------------------------------------------
__global__ __launch_bounds__(256, 1) void metarnn_gemm(
    const float *__restrict__ x, const float *__restrict__ Wih_l,
    const float *__restrict__ Why_l, float *__restrict__ xW,
    float *__restrict__ xH) {
  int w = threadIdx.x >> 6, lane = threadIdx.x & 63;
  int m0 = blockIdx.x * 32;
  int rowL = lane & 15, kg = (lane >> 4) << 3;
  f32x4 acc[2][6] = {};

  for (int kt = 0; kt < 8; ++kt) {
    bf16x8 ah[2], al[2];
    for (int s = 0; s < 2; ++s) {
      const float *xp = x + (size_t)(m0 + s * 16 + rowL) * 256 + kt * 32 + kg;
      u16x8 vh, vl;
#pragma unroll
      for (int j = 0; j < 8; ++j) {
        u16 hi, lo;
        split2(xp[j], hi, lo);
        vh[j] = hi; vl[j] = lo;
      }
      ah[s] = __builtin_bit_cast(bf16x8, vh);
      al[s] = __builtin_bit_cast(bf16x8, vl);
    }
#pragma unroll
    for (int q = 0; q < 6; ++q) {
      int nt = w * 6 + q;
      const float *wp = (nt < 16)
          ? Wih_l + (size_t)(nt * 16 + rowL) * 256 + kt * 32 + kg
          : Why_l + (size_t)((nt - 16) * 16 + rowL) * 512 + kt * 32 + kg;
      u16x8 vbh, vbl;
#pragma unroll
      for (int j = 0; j < 8; ++j) {
        u16 hi, lo;
        split2(wp[j], hi, lo);
        vbh[j] = hi; vbl[j] = lo;
      }
      bf16x8 B0 = __builtin_bit_cast(bf16x8, vbh);
      bf16x8 B1 = __builtin_bit_cast(bf16x8, vbl);
      acc[0][q] = mfma3(ah[0], al[0], B0, B1, acc[0][q]);
      acc[1][q] = mfma3(ah[1], al[1], B0, B1, acc[1][q]);
    }
  }
  for (int s = 0; s < 2; ++s)
    for (int q = 0; q < 6; ++q) {
      int nt = w * 6 + q;
#pragma unroll
      for (int r = 0; r < 4; ++r) {
        int row = m0 + s * 16 + (lane >> 4) * 4 + r;
        if (nt < 16)
          xW[(size_t)row * H_ + nt * 16 + rowL] = acc[s][q][r];
        else
          xH[(size_t)row * HH_ + (nt - 16) * 16 + rowL] = acc[s][q][r];
      }
    }
}

// ---------------------------------------------------------------------------
// scan v12: 16 blocks x 512 threads (8 waves, 2/SIMD). Wave w owns:
//   Whh tiles 2w,2w+1 (hi streamed 3-slot, lo PINNED), HY tile w (hi LDS,
//   lo streamed 3-slot), M tiles gx{2w,2w+1} (hi PINNED, lo streamed).
// Per step: A[P1 aA/aW; ML-g0 issue; P2 hh; xh reload] | BA |
//           [ML-g1 issue] C[d-matmul g0..2 + P6 h] | BC |
// ---------------------------------------------------------------------------
__global__ __launch_bounds__(512, 2) void metarnn_scan(
    const float *__restrict__ xW, const float *__restrict__ xH,
    const u16 *__restrict__ fr, const float *__restrict__ bmain,
    const float *__restrict__ bhy, const float *__restrict__ Wzd,
    const float *__restrict__ bz, float *__restrict__ y,
    float *__restrict__ hlast, int layer, int isLast) {
  __shared__ __align__(16) u16 hc_h[8 * 512];        // h frags kt0..7
  __shared__ __align__(16) u16 hc_l[8 * 512];
  __shared__ __align__(16) u16 hhb_h[2][4 * 512];    // hh frags, t-parity dbuf
  __shared__ __align__(16) u16 hhb_l[2][4 * 512];
  __shared__ __align__(16) u16 hy_lds[8 * 12 * 512]; // HY-hi, 96 KB

  int tid = threadIdx.x, w = tid >> 6, lane = tid & 63;
  int bs = blockIdx.x * 16;
  int rowL = lane & 15, colG = lane >> 4;

  const u16 *FHY = fr + OHY, *FHYl = FHY + PHY;
  const u16 *FWH = fr + OWHH, *FWHl = FWH + PWHH;
  const u16 *FM = fr + OM, *FMl = FM + POM;

  for (int i = tid; i < 8 * 512; i += 512) { hc_h[i] = 0; hc_l[i] = 0; }
  for (int i = tid; i < 4 * 512; i += 512) {
    hhb_h[0][i] = 0; hhb_l[0][i] = 0; hhb_h[1][i] = 0; hhb_l[1][i] = 0;
  }
  // HY-hi -> LDS (once)
  for (int i = tid; i < 8 * 12 * 512 / 8; i += 512) {
    *reinterpret_cast<u32x4 *>(&hy_lds[(size_t)i * 8]) =
        *reinterpret_cast<const u32x4 *>(FHY + (size_t)i * 8);
  }

  // ---- PINNED: Whh-lo (16 frags) + M-hi (24 frags) = 160 regs -------------
  bf16x8 RWL[2][8];
#pragma unroll
  for (int p = 0; p < 2; ++p)
#pragma unroll
    for (int kt = 0; kt < 8; ++kt) {
      long o = ((long)((2 * w + p) * 8 + kt) * 64 + lane) * 8;
      RWL[p][kt] = ldfrag(FWHl + o);
      pin(RWL[p][kt]);
    }
  bf16x8 MH[3][2][4];
#pragma unroll
  for (int g = 0; g < 3; ++g)
#pragma unroll
    for (int p = 0; p < 2; ++p)
#pragma unroll
      for (int kt = 0; kt < 4; ++kt) {
        long o = ((long)((g * 16 + 2 * w + p) * 4 + kt) * 64 + lane) * 8;
        MH[g][p][kt] = ldfrag(FM + o);
        pin(MH[g][p][kt]);
      }

  // ---- biases / db constants (db_g = Wzd_g @ bz_g, computed inline) -------
  int c2 = 16 * w + rowL;                       // hyper col (0..127)
  float bhv = bhy[layer * HH_ + c2];
  float db0v[2], db1v[2], bb2[2];
  {
    const float *WzdL = Wzd + (size_t)layer * 3 * 256 * 32;
    const float *bzL = bz + layer * 3 * 32;
#pragma unroll
    for (int p = 0; p < 2; ++p) {
      int c = 32 * w + 16 * p + rowL;
      float d0 = 0.0f, d1 = 0.0f, d2 = 0.0f;
      for (int ee = 0; ee < 32; ++ee) {
        d0 += WzdL[(size_t)(0 * 256 + c) * 32 + ee] * bzL[0 * 32 + ee];
        d1 += WzdL[(size_t)(1 * 256 + c) * 32 + ee] * bzL[1 * 32 + ee];
        d2 += WzdL[(size_t)(2 * 256 + c) * 32 + ee] * bzL[2 * 32 + ee];
      }
      db0v[p] = d0;
      db1v[p] = d1;
      bb2[p] = bmain[layer * H_ + c] + d2;
    }
  }

  // ---- streamed-weight rotating buffers (slot s holds kt == s mod 3) ------
  bf16x8 bWH[3][2], bYL[3];
#define LOAD_SLOT(S, KT)                                                      \
  {                                                                           \
    long oy = ((long)(w * 12 + (KT)) * 64 + lane) * 8;                        \
    bYL[S] = ldfrag(FHYl + oy);                                               \
    if ((KT) < 8) {                                                           \
      long o0 = ((long)((2 * w) * 8 + (KT)) * 64 + lane) * 8;                 \
      long o1 = ((long)((2 * w + 1) * 8 + (KT)) * 64 + lane) * 8;             \
      bWH[S][0] = ldfrag(FWH + o0);                                           \
      bWH[S][1] = ldfrag(FWH + o1);                                           \
    }                                                                         \
  }
#pragma unroll
  for (int s = 0; s < 3; ++s) LOAD_SLOT(s, s)

  float xhv[4], xwv[2][4];
#pragma unroll
  for (int r = 0; r < 4; ++r) {     // prologue x (t=0)
    size_t row = (size_t)(bs + 4 * colG + r) * T_;
    xhv[r] = xH[row * HH_ + c2];
    xwv[0][r] = xW[row * H_ + 32 * w + rowL];
    xwv[1][r] = xW[row * H_ + 32 * w + 16 + rowL];
  }

  __syncthreads();                  // once; full drain acceptable here

  for (int t = 0; t < T_; ++t) {
    const int pr = t & 1;
    const int tn = (t + 1 < T_) ? t + 1 : t;   // guarded next-step index
    // ---- P1: aA (hcat @ HY^T tile w), aW (h @ Whh^T tiles 2w,2w+1) --------
    f32x4 aAe = {}, aAo = {}, aW0 = {}, aW1 = {};
    __builtin_amdgcn_s_setprio(1);
#pragma unroll
    for (int j = 0; j < 12; ++j) {
      const int s = j % 3;
      bf16x8 ah, al;
      if (j < 8) {
        ah = ldfrag(&hc_h[j * 512 + lane * 8]);
        al = ldfrag(&hc_l[j * 512 + lane * 8]);
      } else {
        ah = ldfrag(&hhb_h[pr ^ 1][(j - 8) * 512 + lane * 8]);
        al = ldfrag(&hhb_l[pr ^ 1][(j - 8) * 512 + lane * 8]);
      }
      bf16x8 yh = ldfrag(&hy_lds[(w * 12 + j) * 512 + lane * 8]);
      if (j & 1) aAo = mfma3(ah, al, yh, bYL[s], aAo);
      else       aAe = mfma3(ah, al, yh, bYL[s], aAe);
      if (j < 8) {
        aW0 = mfma3(ah, al, bWH[s][0], RWL[0][j], aW0);
        aW1 = mfma3(ah, al, bWH[s][1], RWL[1][j], aW1);
      }
      if (j < 9) LOAD_SLOT(s, j + 3)      // prefetch kt=j+3 (distance 3)
    }
    __builtin_amdgcn_s_setprio(0);
    f32x4 aA;
#pragma unroll
    for (int r = 0; r < 4; ++r) aA[r] = aAe[r] + aAo[r];

    // refill slots 0..2 for next step (in flight across BA..BC)
#pragma unroll
    for (int s = 0; s < 3; ++s) LOAD_SLOT(s, s)

    // ---- issue M-lo g0 (consumed in C, ~1000 cyc away) --------------------
    bf16x8 MLa[2][4];
#pragma unroll
    for (int p = 0; p < 2; ++p)
#pragma unroll
      for (int kt = 0; kt < 4; ++kt) {
        long o = ((long)((2 * w + p) * 4 + kt) * 64 + lane) * 8;   // g=0
        MLa[p][kt] = ldfrag(FMl + o);
      }

    // ---- P2: hh_new = tanh(aA + xH + b_hy) -> hhb[pr]; then reload xh -----
    {
      int kfr = w >> 1;
      int hb2 = 2 * (w & 1) + (rowL >> 3);
      int j7 = rowL & 7;
#pragma unroll
      for (int r = 0; r < 4; ++r) {
        float v = tanh_fast(aA[r] + xhv[r] + bhv);
        u16 hi, lo;
        split2(v, hi, lo);
        int di = kfr * 512 + ((4 * colG + r) + 16 * hb2) * 8 + j7;
        hhb_h[pr][di] = hi;
        hhb_l[pr][di] = lo;
      }
    }
#pragma unroll
    for (int r = 0; r < 4; ++r) {   // xh for t+1
      xhv[r] = xH[((size_t)(bs + 4 * colG + r) * T_ + tn) * HH_ + c2];
    }
    block_sync();                          // BA (hh(t) frags visible)

    // ---- issue M-lo g1 ----------------------------------------------------
    bf16x8 MLb[2][4];
#pragma unroll
    for (int p = 0; p < 2; ++p)
#pragma unroll
      for (int kt = 0; kt < 4; ++kt) {
        long o = ((long)((16 + 2 * w + p) * 4 + kt) * 64 + lane) * 8; // g=1
        MLb[p][kt] = ldfrag(FMl + o);
      }

    // ---- C: d_g = hh @ M_g^T + db_g, accumulate arg -----------------------
    bf16x8 hhA[4], hhL[4];
#pragma unroll
    for (int kt = 0; kt < 4; ++kt) {
      hhA[kt] = ldfrag(&hhb_h[pr][kt * 512 + lane * 8]);
      hhL[kt] = ldfrag(&hhb_l[pr][kt * 512 + lane * 8]);
    }
    float arg[2][4];
#pragma unroll
    for (int p = 0; p < 2; ++p)
#pragma unroll
      for (int r = 0; r < 4; ++r) arg[p][r] = bb2[p];
    // g0
#pragma unroll
    for (int p = 0; p < 2; ++p) {
      f32x4 dg = {};
#pragma unroll
      for (int kt = 0; kt < 4; ++kt)
        dg = mfma3(hhA[kt], hhL[kt], MH[0][p][kt], MLa[p][kt], dg);
#pragma unroll
      for (int r = 0; r < 4; ++r)
        arg[p][r] += (dg[r] + db0v[p]) * xwv[p][r];
    }
    // issue M-lo g2 into MLa; reload xw for t+1 (after last use)
#pragma unroll
    for (int p = 0; p < 2; ++p)
#pragma unroll
      for (int kt = 0; kt < 4; ++kt) {
        long o = ((long)((32 + 2 * w + p) * 4 + kt) * 64 + lane) * 8; // g=2
        MLa[p][kt] = ldfrag(FMl + o);
      }
#pragma unroll
    for (int r = 0; r < 4; ++r) {
      size_t row = (size_t)(bs + 4 * colG + r) * T_ + tn;
      xwv[0][r] = xW[row * H_ + 32 * w + rowL];
      xwv[1][r] = xW[row * H_ + 32 * w + 16 + rowL];
    }
    // g1
#pragma unroll
    for (int p = 0; p < 2; ++p) {
      f32x4 dg = {};
#pragma unroll
      for (int kt = 0; kt < 4; ++kt)
        dg = mfma3(hhA[kt], hhL[kt], MH[1][p][kt], MLb[p][kt], dg);
#pragma unroll
      for (int r = 0; r < 4; ++r)
        arg[p][r] += (dg[r] + db1v[p]) * ((p == 0) ? aW0[r] : aW1[r]);
    }
    // g2 (db2 pre-folded into bb2)
#pragma unroll
    for (int p = 0; p < 2; ++p) {
      f32x4 dg = {};
#pragma unroll
      for (int kt = 0; kt < 4; ++kt)
        dg = mfma3(hhA[kt], hhL[kt], MH[2][p][kt], MLa[p][kt], dg);
#pragma unroll
      for (int r = 0; r < 4; ++r) arg[p][r] += dg[r];
    }

    // ---- P6: h_new = tanh(arg), write y, refresh hc frags -----------------
#pragma unroll
    for (int p = 0; p < 2; ++p) {
      int c = 32 * w + 16 * p + rowL;
      int hb6 = 2 * p + (rowL >> 3);
      int j7 = rowL & 7;
#pragma unroll
      for (int r = 0; r < 4; ++r) {
        int m = 4 * colG + r;
        float h = tanh_fast(arg[p][r]);
        size_t gi = (size_t)(bs + m) * T_ + t;
        y[gi * H_ + c] = h;
        if (isLast && t == T_ - 1) hlast[(size_t)(bs + m) * H_ + c] = h;
        u16 hi, lo;
        split2(h, hi, lo);
        int di = (c >> 5) * 512 + (m + 16 * hb6) * 8 + j7;
        hc_h[di] = hi;
        hc_l[di] = lo;
      }
    }
    block_sync();                          // BC (h(t) frags ready for P1(t+1))
  }
#undef LOAD_SLOT
}

// ---------------------------------------------------------------------------
extern "C" void kernel_launch(void *const *d_in, const int *in_sizes, int n_in,
                              void *d_out, int out_size, void *d_ws,
                              size_t ws_size, hipStream_t stream) {
  (void)in_sizes; (void)n_in; (void)out_size; (void)ws_size;
  const float *input  = (const float *)d_in[0];
  const float *Wih    = (const float *)d_in[1];
  const float *Whh    = (const float *)d_in[2];
  const float *b      = (const float *)d_in[3];
  const float *Wih_hy = (const float *)d_in[4];
  const float *Whh_hy = (const float *)d_in[5];
  const float *b_hy   = (const float *)d_in[6];
  const float *Whz    = (const float *)d_in[7];
  const float *bz     = (const float *)d_in[8];
  const float *Wzd    = (const float *)d_in[9];

  float *out = (float *)d_out;
  float *xW = (float *)((char *)d_ws + WS_XW);
  float *xH = (float *)((char *)d_ws + WS_XH);
  u16 *fr = (u16 *)((char *)d_ws + WS_FR);
  float *hlast = out + (size_t)BT * H_;

  metarnn_prep<<<dim3(208), dim3(256), 0, stream>>>(Whh, Wih_hy, Whh_hy, Whz,
                                                    Wzd, fr);
  for (int l = 0; l < 2; ++l) {
    const float *xsrc = (l == 0) ? input : out;   // layer1 reads layer0 output
    const u16 *frl = fr + (size_t)l * LSTRIDE;
    metarnn_gemm<<<dim3(BT / 32), dim3(256), 0, stream>>>(
        xsrc, Wih + (size_t)l * H_ * D_, Wih_hy + (size_t)l * HH_ * (D_ + H_),
        xW, xH);
    metarnn_scan<<<dim3(16), dim3(512), 0, stream>>>(
        xW, xH, frl, b, b_hy, Wzd, bz, out, hlast, l, (l == 1) ? 1 : 0);
  }
}

// Round 12
// 9778.876 us; speedup vs baseline: 4.6979x; 1.4794x over previous
//
#include <hip/hip_runtime.h>

// ---------------------------------------------------------------------------
// MetaRNN (HyperNetwork-conditioned RNN), MI355X gfx950.  v13
//   v4 3-phase scan structure (best verified: 4232us/scan) with P1 made
//   COMPLETELY vmem-free (in-order vmcnt queue: one exposed load in P1
//   stalls all younger consumptions; partial pin removal (v5) proved null,
//   so the lever is total removal):
//   - PINNED: Whh hi+lo (128 regs) + HY-lo (48 regs)  [AGPR bank, as v5]
//   - LDS:    HY-hi (96KB) + Whz-hi (24KB)  -> 158KB block
//   - Streamed at phase boundaries only (monotone issue/consume order):
//     Whz-lo end-P1 -> P3;  Wzd D0 post-BA -> g0, D1 post-BB -> g1,
//     D2 mid-P5 (reuses D0 regs) -> g2;  xh after P2, xw after g0 (1 step).
//   prep/gemm: v12's validated versions (raw-weight gemm, smaller ws).
//   Split-bf16 3-term products (absmax 0.0039 validated v1-v12).
// ---------------------------------------------------------------------------

#define DEVI __device__ __forceinline__

typedef __bf16 bf16x8 __attribute__((ext_vector_type(8)));
typedef float f32x4 __attribute__((ext_vector_type(4)));
typedef unsigned short u16;
typedef unsigned int u32;
typedef u32 u32x4 __attribute__((ext_vector_type(4)));
typedef u16 u16x8 __attribute__((ext_vector_type(8)));

constexpr int B_ = 256, T_ = 512, D_ = 256, H_ = 256, HH_ = 128, E_ = 32;
constexpr int BT = B_ * T_;

// fragment-buffer offsets (u16 elements), per layer — scan-only weights
constexpr int OHY = 0,       PHY = 8 * 12 * 512;   // [U_hy|Whh_hy] [8nt][12kt]
constexpr int OWHH = 98304,  PWHH = 16 * 8 * 512;  // Whh   [16nt][8kt]
constexpr int OWHZ = 229376, PWHZ = 6 * 4 * 512;   // Whz   [6nt][4kt]
constexpr int OWZD = 253952, PWZD = 48 * 512;      // Wzd   [3g][16nt][1kt]
constexpr int LSTRIDE = 303104;                    // u16 per layer

constexpr size_t WS_XW = 0;
constexpr size_t WS_XH = (size_t)BT * H_ * 4;
constexpr size_t WS_FR = WS_XH + (size_t)BT * HH_ * 4;
// total ws usage: WS_FR + 2*LSTRIDE*2 B = 202,539,008  (< v12's validated)

DEVI u16 f2bf(float v) {            // round-to-nearest-even fp32 -> bf16 bits
  u32 u = __float_as_uint(v);
  u += 0x7fffu + ((u >> 16) & 1u);
  return (u16)(u >> 16);
}
DEVI float bf2f(u16 s) { return __uint_as_float(((u32)s) << 16); }
DEVI void split2(float v, u16 &hi, u16 &lo) {
  hi = f2bf(v);
  lo = f2bf(v - bf2f(hi));          // exact subtraction
}
DEVI bf16x8 ldfrag(const u16 *p) {
  u32x4 v = *reinterpret_cast<const u32x4 *>(p);
  return __builtin_bit_cast(bf16x8, v);
}
// Pin a fragment in registers (opaque to the optimizer -> no remat/sink).
DEVI void pin(bf16x8 &x) {
  u32x4 t = __builtin_bit_cast(u32x4, x);
  asm volatile("" : "+v"(t));
  x = __builtin_bit_cast(bf16x8, t);
}
DEVI f32x4 mfma3(bf16x8 ah, bf16x8 al, bf16x8 bh, bf16x8 bl, f32x4 c) {
  c = __builtin_amdgcn_mfma_f32_16x16x32_bf16(ah, bh, c, 0, 0, 0);
  c = __builtin_amdgcn_mfma_f32_16x16x32_bf16(ah, bl, c, 0, 0, 0);
  c = __builtin_amdgcn_mfma_f32_16x16x32_bf16(al, bh, c, 0, 0, 0);
  return c;
}
DEVI float tanh_fast(float x) {
  float e = __expf(2.0f * x);       // inf-safe: ->1 / ->-1 at extremes
  return 1.0f - 2.0f / (e + 1.0f);
}
// Raw barrier: LDS ordering enforced (lgkmcnt(0)), vmem loads stay in flight.
DEVI void block_sync() {
  asm volatile("s_waitcnt lgkmcnt(0)\n\ts_barrier" ::: "memory");
}

// ---------------------------------------------------------------------------
// prep: split scan weights to bf16 hi/lo 16x16x32 B-fragments.
// fragment: element j, lane l  <-  W[nt*16 + (l&15), kt*32 + (l>>4)*8 + j]
// entries/layer: HY 96, Whh 128, Whz 24, Wzd 48 -> 296
// ---------------------------------------------------------------------------
__global__ void metarnn_prep(const float *__restrict__ Whh,
                             const float *__restrict__ Wih_hy,
                             const float *__restrict__ Whh_hy,
                             const float *__restrict__ Whz,
                             const float *__restrict__ Wzd,
                             u16 *__restrict__ fr) {
  int gid = blockIdx.x * 256 + threadIdx.x;
  int lane = gid & 63;
  int e = gid >> 6;
  if (e >= 2 * 296) return;
  int l = e / 296, r = e - l * 296;
  u16 *base = fr + (size_t)l * LSTRIDE;
  int rowL = lane & 15, kg = (lane >> 4) << 3;

  if (r < 96) {             // HY concat [U_hy | Whh_hy]  [HH, 384]
    int nt = r / 12, kt = r - nt * 12;
    u16 *dh = base + OHY, *dl = dh + PHY;
    int row = nt * 16 + rowL;
    long dof = ((long)(nt * 12 + kt) * 64 + lane) * 8;
    for (int j = 0; j < 8; ++j) {
      int k = kt * 32 + kg + j;
      float v = (k < 256)
                    ? Wih_hy[((size_t)l * HH_ + row) * (D_ + H_) + 256 + k]
                    : Whh_hy[((size_t)l * HH_ + row) * HH_ + (k - 256)];
      u16 hi, lo;
      split2(v, hi, lo);
      dh[dof + j] = hi;
      dl[dof + j] = lo;
    }
  } else if (r < 224) {     // Whh [H,H]
    int m = r - 96;
    int nt = m >> 3, kt = m & 7;
    u16 *dh = base + OWHH, *dl = dh + PWHH;
    int row = nt * 16 + rowL;
    long dof = ((long)(nt * 8 + kt) * 64 + lane) * 8;
    const float *src = Whh + (size_t)l * H_ * H_;
    for (int j = 0; j < 8; ++j) {
      u16 hi, lo;
      split2(src[(size_t)row * H_ + kt * 32 + kg + j], hi, lo);
      dh[dof + j] = hi;
      dl[dof + j] = lo;
    }
  } else if (r < 248) {     // Whz flat [96, 128]
    int m = r - 224;
    int nt = m >> 2, kt = m & 3;
    u16 *dh = base + OWHZ, *dl = dh + PWHZ;
    int row = nt * 16 + rowL;
    long dof = ((long)(nt * 4 + kt) * 64 + lane) * 8;
    const float *src = Whz + (size_t)l * 3 * E_ * HH_;
    for (int j = 0; j < 8; ++j) {
      u16 hi, lo;
      split2(src[(size_t)row * HH_ + kt * 32 + kg + j], hi, lo);
      dh[dof + j] = hi;
      dl[dof + j] = lo;
    }
  } else {                  // Wzd per g: [H, E]
    int m = r - 248;
    int g = m >> 4, nt = m & 15;
    u16 *dh = base + OWZD + g * 16 * 512, *dl = dh + PWZD;
    int row = nt * 16 + rowL;
    long dof = ((long)nt * 64 + lane) * 8;
    const float *src = Wzd + (size_t)(l * 3 + g) * H_ * E_;
    for (int j = 0; j < 8; ++j) {
      u16 hi, lo;
      split2(src[(size_t)row * E_ + kg + j], hi, lo);
      dh[dof + j] = hi;
      dl[dof + j] = lo;
    }
  }
}

// ---------------------------------------------------------------------------
// GEMM: xW[m,0:256], xH[m,0:128] = x[m,0:256] @ {Wih, Wih_hy_x}^T
// Weights read raw from d_in, split2 on the fly (bit-identical fragments).
// ---------------------------------------------------------------------------
__global__ __launch_bounds__(256, 1) void metarnn_gemm(
    const float *__restrict__ x, const float *__restrict__ Wih_l,
    const float *__restrict__ Why_l, float *__restrict__ xW,
    float *__restrict__ xH) {
  int w = threadIdx.x >> 6, lane = threadIdx.x & 63;
  int m0 = blockIdx.x * 32;
  int rowL = lane & 15, kg = (lane >> 4) << 3;
  f32x4 acc[2][6] = {};

  for (int kt = 0; kt < 8; ++kt) {
    bf16x8 ah[2], al[2];
    for (int s = 0; s < 2; ++s) {
      const float *xp = x + (size_t)(m0 + s * 16 + rowL) * 256 + kt * 32 + kg;
      u16x8 vh, vl;
#pragma unroll
      for (int j = 0; j < 8; ++j) {
        u16 hi, lo;
        split2(xp[j], hi, lo);
        vh[j] = hi; vl[j] = lo;
      }
      ah[s] = __builtin_bit_cast(bf16x8, vh);
      al[s] = __builtin_bit_cast(bf16x8, vl);
    }
#pragma unroll
    for (int q = 0; q < 6; ++q) {
      int nt = w * 6 + q;
      const float *wp = (nt < 16)
          ? Wih_l + (size_t)(nt * 16 + rowL) * 256 + kt * 32 + kg
          : Why_l + (size_t)((nt - 16) * 16 + rowL) * 512 + kt * 32 + kg;
      u16x8 vbh, vbl;
#pragma unroll
      for (int j = 0; j < 8; ++j) {
        u16 hi, lo;
        split2(wp[j], hi, lo);
        vbh[j] = hi; vbl[j] = lo;
      }
      bf16x8 B0 = __builtin_bit_cast(bf16x8, vbh);
      bf16x8 B1 = __builtin_bit_cast(bf16x8, vbl);
      acc[0][q] = mfma3(ah[0], al[0], B0, B1, acc[0][q]);
      acc[1][q] = mfma3(ah[1], al[1], B0, B1, acc[1][q]);
    }
  }
  for (int s = 0; s < 2; ++s)
    for (int q = 0; q < 6; ++q) {
      int nt = w * 6 + q;
#pragma unroll
      for (int r = 0; r < 4; ++r) {
        int row = m0 + s * 16 + (lane >> 4) * 4 + r;
        if (nt < 16)
          xW[(size_t)row * H_ + nt * 16 + rowL] = acc[s][q][r];
        else
          xH[(size_t)row * HH_ + (nt - 16) * 16 + rowL] = acc[s][q][r];
      }
    }
}

// ---------------------------------------------------------------------------
// scan v13: 16 blocks x 512 threads (8 waves, 2/SIMD). Wave w owns:
//   Whh tiles 2w,2w+1 (hi+lo PINNED), HY tile w (hi LDS, lo PINNED),
//   Whz tile w (hi LDS, lo streamed), Wzd tiles gx{2w,2w+1} (streamed).
// Per step: P1 aA/aW [NO VMEM] ; zSl issue ; P2 hh ; xh reload | BA |
//           D0 issue ; P3 z | BB | D1 issue ; P5 g0 ; D2+xw issue ;
//           g1 ; g2 ; P6 h | BC |
// ---------------------------------------------------------------------------
__global__ __launch_bounds__(512, 2) void metarnn_scan(
    const float *__restrict__ xW, const float *__restrict__ xH,
    const u16 *__restrict__ fr, const float *__restrict__ bmain,
    const float *__restrict__ bhy, const float *__restrict__ bz,
    float *__restrict__ y, float *__restrict__ hlast, int layer, int isLast) {
  __shared__ __align__(16) u16 hc_h[8 * 512];        // h frags kt0..7
  __shared__ __align__(16) u16 hc_l[8 * 512];
  __shared__ __align__(16) u16 hhb_h[2][4 * 512];    // hh frags, t-parity dbuf
  __shared__ __align__(16) u16 hhb_l[2][4 * 512];
  __shared__ __align__(16) u16 zf_h[3 * 512];
  __shared__ __align__(16) u16 zf_l[3 * 512];
  __shared__ __align__(16) u16 hy_lds[8 * 12 * 512]; // HY-hi, 96 KB
  __shared__ __align__(16) u16 whz_lds[6 * 4 * 512]; // Whz-hi, 24 KB

  int tid = threadIdx.x, w = tid >> 6, lane = tid & 63;
  int bs = blockIdx.x * 16;
  int rowL = lane & 15, colG = lane >> 4;

  const u16 *FHY = fr + OHY, *FHYl = FHY + PHY;
  const u16 *FWH = fr + OWHH, *FWHl = FWH + PWHH;
  const u16 *FWZ = fr + OWHZ, *FWZl = FWZ + PWHZ;
  const u16 *FZD = fr + OWZD, *FZDl = FZD + PWZD;

  for (int i = tid; i < 8 * 512; i += 512) { hc_h[i] = 0; hc_l[i] = 0; }
  for (int i = tid; i < 4 * 512; i += 512) {
    hhb_h[0][i] = 0; hhb_l[0][i] = 0; hhb_h[1][i] = 0; hhb_l[1][i] = 0;
  }
  for (int i = tid; i < 3 * 512; i += 512) { zf_h[i] = 0; zf_l[i] = 0; }
  // HY-hi and Whz-hi -> LDS (once)
  for (int i = tid; i < 8 * 12 * 512 / 8; i += 512) {
    *reinterpret_cast<u32x4 *>(&hy_lds[(size_t)i * 8]) =
        *reinterpret_cast<const u32x4 *>(FHY + (size_t)i * 8);
  }
  for (int i = tid; i < 6 * 4 * 512 / 8; i += 512) {
    *reinterpret_cast<u32x4 *>(&whz_lds[(size_t)i * 8]) =
        *reinterpret_cast<const u32x4 *>(FWZ + (size_t)i * 8);
  }

  // ---- PINNED: Whh hi+lo (128 regs) + HY-lo (48 regs) ---------------------
  bf16x8 RWH[2][8], RWL[2][8];
#pragma unroll
  for (int p = 0; p < 2; ++p)
#pragma unroll
    for (int kt = 0; kt < 8; ++kt) {
      long o = ((long)((2 * w + p) * 8 + kt) * 64 + lane) * 8;
      RWH[p][kt] = ldfrag(FWH + o);  pin(RWH[p][kt]);
      RWL[p][kt] = ldfrag(FWHl + o); pin(RWL[p][kt]);
    }
  bf16x8 RYL[12];
#pragma unroll
  for (int j = 0; j < 12; ++j) {
    RYL[j] = ldfrag(FHYl + ((long)(w * 12 + j) * 64 + lane) * 8);
    pin(RYL[j]);
  }

  // ---- hoisted biases -----------------------------------------------------
  int c2 = 16 * w + rowL;                       // hyper col (0..127)
  int wz = (w < 6) ? w : 0;
  float bhv = bhy[layer * HH_ + c2];
  float bzv = (w < 6) ? bz[layer * 3 * E_ + c2] : 0.0f;
  float bbv[2];
  bbv[0] = bmain[layer * H_ + 32 * w + rowL];
  bbv[1] = bmain[layer * H_ + 32 * w + 16 + rowL];

  float xhv[4], xwv[2][4];
#pragma unroll
  for (int r = 0; r < 4; ++r) {     // prologue x (t=0)
    size_t row = (size_t)(bs + 4 * colG + r) * T_;
    xhv[r] = xH[row * HH_ + c2];
    xwv[0][r] = xW[row * H_ + 32 * w + rowL];
    xwv[1][r] = xW[row * H_ + 32 * w + 16 + rowL];
  }

  __syncthreads();                  // once; full drain acceptable here

  for (int t = 0; t < T_; ++t) {
    const int pr = t & 1;
    const int tn = (t + 1 < T_) ? t + 1 : t;
    // ---- P1: aA (hcat @ HY^T tile w), aW (h @ Whh^T) — ZERO vmem ----------
    f32x4 aAe = {}, aAo = {}, aW0 = {}, aW1 = {};
    __builtin_amdgcn_s_setprio(1);
#pragma unroll
    for (int j = 0; j < 12; ++j) {
      bf16x8 ah, al;
      if (j < 8) {
        ah = ldfrag(&hc_h[j * 512 + lane * 8]);
        al = ldfrag(&hc_l[j * 512 + lane * 8]);
      } else {
        ah = ldfrag(&hhb_h[pr ^ 1][(j - 8) * 512 + lane * 8]);
        al = ldfrag(&hhb_l[pr ^ 1][(j - 8) * 512 + lane * 8]);
      }
      bf16x8 yh = ldfrag(&hy_lds[(w * 12 + j) * 512 + lane * 8]);
      if (j & 1) aAo = mfma3(ah, al, yh, RYL[j], aAo);
      else       aAe = mfma3(ah, al, yh, RYL[j], aAe);
      if (j < 8) {
        aW0 = mfma3(ah, al, RWH[0][j], RWL[0][j], aW0);
        aW1 = mfma3(ah, al, RWH[1][j], RWL[1][j], aW1);
      }
    }
    __builtin_amdgcn_s_setprio(0);
    f32x4 aA;
#pragma unroll
    for (int r = 0; r < 4; ++r) aA[r] = aAe[r] + aAo[r];

    // ---- issue Whz-lo (consumed P3 across BA) -----------------------------
    bf16x8 zSl[4];
#pragma unroll
    for (int kk = 0; kk < 4; ++kk)
      zSl[kk] = ldfrag(FWZl + ((long)(wz * 4 + kk) * 64 + lane) * 8);

    // ---- P2: hh_new = tanh(aA + xH + b_hy) -> hhb[pr]; then reload xh -----
    {
      int kfr = w >> 1;
      int hb2 = 2 * (w & 1) + (rowL >> 3);
      int j7 = rowL & 7;
#pragma unroll
      for (int r = 0; r < 4; ++r) {
        float v = tanh_fast(aA[r] + xhv[r] + bhv);
        u16 hi, lo;
        split2(v, hi, lo);
        int di = kfr * 512 + ((4 * colG + r) + 16 * hb2) * 8 + j7;
        hhb_h[pr][di] = hi;
        hhb_l[pr][di] = lo;
      }
    }
#pragma unroll
    for (int r = 0; r < 4; ++r) {   // xh for t+1 (full-step cover)
      xhv[r] = xH[((size_t)(bs + 4 * colG + r) * T_ + tn) * HH_ + c2];
    }
    block_sync();                          // BA (hh(t) frags visible)

    // ---- issue Wzd g0 (consumed P5-g0 across BB) --------------------------
    bf16x8 D0h[2], D0l[2];
#pragma unroll
    for (int p = 0; p < 2; ++p) {
      long o = ((long)(2 * w + p) * 64 + lane) * 8;
      D0h[p] = ldfrag(FZD + o);
      D0l[p] = ldfrag(FZDl + o);
    }

    // ---- P3: z = hh_new @ Whz^T + bz -> zf frags (waves 0..5) -------------
    if (w < 6) {
      f32x4 aZ = {};
#pragma unroll
      for (int kk = 0; kk < 4; ++kk) {
        bf16x8 ah = ldfrag(&hhb_h[pr][kk * 512 + lane * 8]);
        bf16x8 al = ldfrag(&hhb_l[pr][kk * 512 + lane * 8]);
        bf16x8 zh = ldfrag(&whz_lds[(w * 4 + kk) * 512 + lane * 8]);
        aZ = mfma3(ah, al, zh, zSl[kk], aZ);
      }
      int g = c2 >> 5;                     // c2 = 16w+rowL in [0,96)
      int hb3 = 2 * (w & 1) + (rowL >> 3);
      int j7 = rowL & 7;
#pragma unroll
      for (int r = 0; r < 4; ++r) {
        float v = aZ[r] + bzv;
        u16 hi, lo;
        split2(v, hi, lo);
        int di = g * 512 + ((4 * colG + r) + 16 * hb3) * 8 + j7;
        zf_h[di] = hi;
        zf_l[di] = lo;
      }
    }
    block_sync();                          // BB (zf ready)

    // ---- issue Wzd g1 (consumed P5-g1; cover = g0 compute) ----------------
    bf16x8 D1h[2], D1l[2];
#pragma unroll
    for (int p = 0; p < 2; ++p) {
      long o = ((long)(16 + 2 * w + p) * 64 + lane) * 8;
      D1h[p] = ldfrag(FZD + o);
      D1l[p] = ldfrag(FZDl + o);
    }

    // ---- P5: d_g = z @ Wzd_g^T, accumulate h-arg over g -------------------
    float arg[2][4];
#pragma unroll
    for (int p = 0; p < 2; ++p)
#pragma unroll
      for (int r = 0; r < 4; ++r) arg[p][r] = bbv[p];
    {
      bf16x8 zh = ldfrag(&zf_h[0 * 512 + lane * 8]);
      bf16x8 zl = ldfrag(&zf_l[0 * 512 + lane * 8]);
#pragma unroll
      for (int p = 0; p < 2; ++p) {
        f32x4 zero = {};
        f32x4 dg = mfma3(zh, zl, D0h[p], D0l[p], zero);
#pragma unroll
        for (int r = 0; r < 4; ++r) arg[p][r] += dg[r] * xwv[p][r];
      }
    }
    // issue Wzd g2 into D0's registers; reload xw (after last use)
#pragma unroll
    for (int p = 0; p < 2; ++p) {
      long o = ((long)(32 + 2 * w + p) * 64 + lane) * 8;
      D0h[p] = ldfrag(FZD + o);
      D0l[p] = ldfrag(FZDl + o);
    }
#pragma unroll
    for (int r = 0; r < 4; ++r) {
      size_t row = (size_t)(bs + 4 * colG + r) * T_ + tn;
      xwv[0][r] = xW[row * H_ + 32 * w + rowL];
      xwv[1][r] = xW[row * H_ + 32 * w + 16 + rowL];
    }
    {
      bf16x8 zh = ldfrag(&zf_h[1 * 512 + lane * 8]);
      bf16x8 zl = ldfrag(&zf_l[1 * 512 + lane * 8]);
#pragma unroll
      for (int p = 0; p < 2; ++p) {
        f32x4 zero = {};
        f32x4 dg = mfma3(zh, zl, D1h[p], D1l[p], zero);
#pragma unroll
        for (int r = 0; r < 4; ++r)
          arg[p][r] += dg[r] * ((p == 0) ? aW0[r] : aW1[r]);
      }
    }
    {
      bf16x8 zh = ldfrag(&zf_h[2 * 512 + lane * 8]);
      bf16x8 zl = ldfrag(&zf_l[2 * 512 + lane * 8]);
#pragma unroll
      for (int p = 0; p < 2; ++p) {
        f32x4 zero = {};
        f32x4 dg = mfma3(zh, zl, D0h[p], D0l[p], zero);
#pragma unroll
        for (int r = 0; r < 4; ++r) arg[p][r] += dg[r];
      }
    }

    // ---- P6: h_new = tanh(arg), write y, refresh hc frags -----------------
#pragma unroll
    for (int p = 0; p < 2; ++p) {
      int c = 32 * w + 16 * p + rowL;
      int hb6 = 2 * p + (rowL >> 3);
      int j7 = rowL & 7;
#pragma unroll
      for (int r = 0; r < 4; ++r) {
        int m = 4 * colG + r;
        float h = tanh_fast(arg[p][r]);
        size_t gi = (size_t)(bs + m) * T_ + t;
        y[gi * H_ + c] = h;
        if (isLast && t == T_ - 1) hlast[(size_t)(bs + m) * H_ + c] = h;
        u16 hi, lo;
        split2(h, hi, lo);
        int di = (c >> 5) * 512 + (m + 16 * hb6) * 8 + j7;
        hc_h[di] = hi;
        hc_l[di] = lo;
      }
    }
    block_sync();                          // BC (h(t) frags ready for P1(t+1))
  }
}

// ---------------------------------------------------------------------------
extern "C" void kernel_launch(void *const *d_in, const int *in_sizes, int n_in,
                              void *d_out, int out_size, void *d_ws,
                              size_t ws_size, hipStream_t stream) {
  (void)in_sizes; (void)n_in; (void)out_size; (void)ws_size;
  const float *input  = (const float *)d_in[0];
  const float *Wih    = (const float *)d_in[1];
  const float *Whh    = (const float *)d_in[2];
  const float *b      = (const float *)d_in[3];
  const float *Wih_hy = (const float *)d_in[4];
  const float *Whh_hy = (const float *)d_in[5];
  const float *b_hy   = (const float *)d_in[6];
  const float *Whz    = (const float *)d_in[7];
  const float *bz     = (const float *)d_in[8];
  const float *Wzd    = (const float *)d_in[9];

  float *out = (float *)d_out;
  float *xW = (float *)((char *)d_ws + WS_XW);
  float *xH = (float *)((char *)d_ws + WS_XH);
  u16 *fr = (u16 *)((char *)d_ws + WS_FR);
  float *hlast = out + (size_t)BT * H_;

  metarnn_prep<<<dim3(148), dim3(256), 0, stream>>>(Whh, Wih_hy, Whh_hy, Whz,
                                                    Wzd, fr);
  for (int l = 0; l < 2; ++l) {
    const float *xsrc = (l == 0) ? input : out;   // layer1 reads layer0 output
    const u16 *frl = fr + (size_t)l * LSTRIDE;
    metarnn_gemm<<<dim3(BT / 32), dim3(256), 0, stream>>>(
        xsrc, Wih + (size_t)l * H_ * D_, Wih_hy + (size_t)l * HH_ * (D_ + H_),
        xW, xH);
    metarnn_scan<<<dim3(16), dim3(512), 0, stream>>>(
        xW, xH, frl, b, b_hy, bz, out, hlast, l, (l == 1) ? 1 : 0);
  }
}